// Round 1
// baseline (11160.122 us; speedup 1.0000x reference)
//
#include <hip/hip_runtime.h>
#include <hip/hip_bf16.h>

// ---- problem constants ----
namespace {
constexpr int nB = 64, nT = 64, nHUMAN = 64, nIN = 8;
constexpr int nHS = 1024, nES = 1024, nK = 7;
constexpr long N_PSI = 1123776;
constexpr long SZ_WHH = 1048576;       // psi region 0: (1024,1024)
constexpr long REST_SZ = 75200;        // per-sample remaining psi elems
constexpr long R_BH = 0;               // (1024,)
constexpr long R_WIH = 1024;           // (8,1024)
constexpr long R_C = 9216;             // (1024,64)
constexpr long R_D = 74752;            // (8,56)
}

// ---------- one-time transpose (rows,cols) -> out[(c)*rows + r] ----------
__global__ void transpose_k(const float* __restrict__ in, float* __restrict__ out,
                            int rows, int cols) {
  __shared__ float tile[32][33];
  int x = blockIdx.x * 32 + threadIdx.x;   // col
  int y = blockIdx.y * 32 + threadIdx.y;   // row
  #pragma unroll
  for (int i = 0; i < 32; i += 8)
    if ((y + i) < rows && x < cols) tile[threadIdx.y + i][threadIdx.x] = in[(long)(y + i) * cols + x];
  __syncthreads();
  x = blockIdx.y * 32 + threadIdx.x;       // new col = old row
  y = blockIdx.x * 32 + threadIdx.y;       // new row = old col
  #pragma unroll
  for (int i = 0; i < 32; i += 8)
    if ((y + i) < cols && x < rows) out[(long)(y + i) * rows + x] = tile[threadIdx.x][threadIdx.y + i];
}

// ---------- encoder GRU step (torch GRUCell, gate order r,z,n) ----------
__global__ __launch_bounds__(256) void enc_step_k(
    const float* __restrict__ h_in, float* __restrict__ h_out,
    const float* __restrict__ outputs,     // (B,T,64)
    const float* __restrict__ WtWhh,       // (1024,3072) = enc_Whh^T
    const float* __restrict__ WtWih,       // (64,3072)   = enc_Wih^T
    const float* __restrict__ bih, const float* __restrict__ bhh, int t) {
  int b = blockIdx.x >> 2;
  int e = (blockIdx.x & 3) * 256 + threadIdx.x;
  __shared__ float hs[1024];
  __shared__ float xs[64];
  for (int i = threadIdx.x; i < 1024; i += 256) hs[i] = h_in[b * 1024 + i];
  if (threadIdx.x < 64) xs[threadIdx.x] = outputs[((long)b * nT + t) * 64 + threadIdx.x];
  __syncthreads();
  float ar = 0.f, az = 0.f, an = 0.f;
  const float* W = WtWhh + e;
  #pragma unroll 4
  for (int h = 0; h < 1024; ++h) {
    float hv = hs[h];
    ar += hv * W[(long)h * 3072];
    az += hv * W[(long)h * 3072 + 1024];
    an += hv * W[(long)h * 3072 + 2048];
  }
  float xr = bih[e], xz = bih[e + 1024], xn = bih[e + 2048];
  const float* Wx = WtWih + e;
  #pragma unroll
  for (int i = 0; i < 64; ++i) {
    float xv = xs[i];
    xr += xv * Wx[(long)i * 3072];
    xz += xv * Wx[(long)i * 3072 + 1024];
    xn += xv * Wx[(long)i * 3072 + 2048];
  }
  ar += bhh[e]; az += bhh[e + 1024]; an += bhh[e + 2048];
  float r = 1.f / (1.f + __expf(-(xr + ar)));
  float z = 1.f / (1.f + __expf(-(xz + az)));
  float n = tanhf(xn + r * an);
  h_out[b * 1024 + e] = (1.f - z) * n + z * hs[e];
}

// ---------- latent: mu, logstd, z ----------
__global__ void latent_k(const float* __restrict__ h_enc,
                         const float* __restrict__ to_mu, const float* __restrict__ to_lsig,
                         const float* __restrict__ lsig_bias, const float* __restrict__ eps,
                         float* __restrict__ out_mu, float* __restrict__ out_lsig,
                         float* __restrict__ zlat) {
  int b = blockIdx.x;
  __shared__ float hs[1024];
  for (int i = threadIdx.x; i < 1024; i += blockDim.x) hs[i] = h_enc[b * 1024 + i];
  __syncthreads();
  int k = threadIdx.x;
  if (k < nK) {
    float am = 0.f, as = 0.f;
    for (int h = 0; h < 1024; ++h) { float hv = hs[h]; am += hv * to_mu[h * nK + k]; as += hv * to_lsig[h * nK + k]; }
    float ls = as + lsig_bias[k];
    out_mu[b * nK + k] = am;
    out_lsig[b * nK + k] = ls;
    zlat[b * nK + k] = am + eps[b * nK + k] * __expf(ls);
  }
}

// ---------- hypernet layers 1-2: a2 = tanh(z@W1+b1)@W2 + b2 ----------
__global__ __launch_bounds__(256) void hyper_k(const float* __restrict__ zlat,
                                               const float* __restrict__ W1, const float* __restrict__ b1,
                                               const float* __restrict__ W2, const float* __restrict__ b2,
                                               float* __restrict__ a2out) {
  int b = blockIdx.x;
  __shared__ float a1[1024];
  __shared__ float zv[nK];
  if (threadIdx.x < nK) zv[threadIdx.x] = zlat[b * nK + threadIdx.x];
  __syncthreads();
  for (int j = threadIdx.x; j < 1024; j += 256) {
    float acc = b1[j];
    #pragma unroll
    for (int i = 0; i < nK; ++i) acc += zv[i] * W1[i * 1024 + j];
    a1[j] = tanhf(acc);
  }
  __syncthreads();
  int l = threadIdx.x >> 3;       // 0..31
  int s = threadIdx.x & 7;
  if (l < 30) {
    float acc = 0.f;
    for (int j = s; j < 1024; j += 8) acc += a1[j] * W2[j * 30 + l];
    acc += __shfl_xor(acc, 4);
    acc += __shfl_xor(acc, 2);
    acc += __shfl_xor(acc, 1);
    if (s == 0) a2out[b * 30 + l] = acc + b2[l];
  }
}

// ---------- psi materialization: Whh region bf16, rest fp32 ----------
__global__ __launch_bounds__(256) void psi_k(const float* __restrict__ a2,
                                             const float* __restrict__ W3, const float* __restrict__ b3,
                                             __hip_bfloat16* __restrict__ WhhB, float* __restrict__ Rest) {
  __shared__ float sa[64 * 30];
  for (int i = threadIdx.x; i < 64 * 30; i += 256) sa[i] = a2[i];
  long n = (long)blockIdx.x * 256 + threadIdx.x;
  __syncthreads();
  if (n >= N_PSI) return;
  float w[30];
  #pragma unroll
  for (int l = 0; l < 30; ++l) w[l] = W3[(long)l * N_PSI + n];
  float bb = b3[n];
  bool isWhh = (n < SZ_WHH);
  for (int b = 0; b < 64; ++b) {
    float acc = bb;
    const float* ab = &sa[b * 30];
    #pragma unroll
    for (int l = 0; l < 30; ++l) acc += ab[l] * w[l];
    if (isWhh) WhhB[(long)b * SZ_WHH + n] = __float2bfloat16(acc);
    else       Rest[(long)b * REST_SZ + (n - SZ_WHH)] = acc;
  }
}

// ---------- decoder GRU step (z first, r second; per-sample Whh_b) ----------
__global__ __launch_bounds__(256) void dec_step_k(
    const float* __restrict__ h_in, float* __restrict__ h_out,
    const float* __restrict__ inputs,        // (B,T,8)
    const float* __restrict__ gWih,          // (8,2048)
    const float* __restrict__ gWhh,          // (1024,2048)
    const float* __restrict__ gbias,         // (2048,)
    const __hip_bfloat16* __restrict__ WhhB, // (B,1024,1024) bf16
    const float* __restrict__ Rest,          // (B,75200)
    float* __restrict__ dec_seq, int t) {
  int b = blockIdx.x >> 2;
  int k = (blockIdx.x & 3) * 256 + threadIdx.x;
  __shared__ float hs[1024];
  __shared__ float xs[8];
  for (int i = threadIdx.x; i < 1024; i += 256) hs[i] = h_in[b * 1024 + i];
  if (threadIdx.x < 8) xs[threadIdx.x] = inputs[((long)b * nT + t) * 8 + threadIdx.x];
  __syncthreads();
  float az = 0.f, ar = 0.f, aw = 0.f;
  const float* Wz = gWhh + k;
  const __hip_bfloat16* Wp = WhhB + (long)b * SZ_WHH + k;
  #pragma unroll 4
  for (int h = 0; h < 1024; ++h) {
    float hv = hs[h];
    az += hv * Wz[(long)h * 2048];
    ar += hv * Wz[(long)h * 2048 + 1024];
    aw += hv * __bfloat162float(Wp[(long)h * 1024]);
  }
  float gz = gbias[k], gr = gbias[1024 + k], xw = 0.f;
  const float* RB = Rest + (long)b * REST_SZ;
  #pragma unroll
  for (int i = 0; i < 8; ++i) {
    float xv = xs[i];
    gz += xv * gWih[i * 2048 + k];
    gr += xv * gWih[i * 2048 + 1024 + k];
    xw += xv * RB[R_WIH + (long)i * 1024 + k];
  }
  float zt = 1.f / (1.f + __expf(-(gz + az)));
  float rt = 1.f / (1.f + __expf(-(gr + ar)));
  float hW = aw + RB[R_BH + k];
  float eta = tanhf(xw + rt * tanhf(hW));
  float hn = zt * hs[k] + (1.f - zt) * eta;
  h_out[b * 1024 + k] = hn;
  dec_seq[((long)b * nT + t) * 1024 + k] = hn;
}

// ---------- readout: yhats = dec_seq@C_b + [inputs | x@D_b] ----------
__global__ __launch_bounds__(64) void readout_k(
    const float* __restrict__ dec_seq, const float* __restrict__ inputs,
    const float* __restrict__ Rest, float* __restrict__ yhats) {
  int bt = blockIdx.x; int b = bt >> 6;
  int m = threadIdx.x;
  __shared__ float ss[1024];
  for (int i = threadIdx.x; i < 1024; i += 64) ss[i] = dec_seq[(long)bt * 1024 + i];
  __syncthreads();
  const float* C = Rest + (long)b * REST_SZ + R_C;
  float acc = 0.f;
  #pragma unroll 4
  for (int h = 0; h < 1024; ++h) acc += ss[h] * C[(long)h * 64 + m];
  if (m < 8) {
    acc += inputs[(long)bt * 8 + m];
  } else {
    const float* D = Rest + (long)b * REST_SZ + R_D;
    #pragma unroll
    for (int i = 0; i < 8; ++i) acc += inputs[(long)bt * 8 + i] * D[i * 56 + (m - 8)];
  }
  yhats[(long)bt * 64 + m] = acc;
}

__global__ void copy_states_k(const float* __restrict__ dec_seq, float* __restrict__ states) {
  int i = blockIdx.x * 256 + threadIdx.x;   // 65536 = B*HS
  int b = i >> 10, h = i & 1023;
  states[i] = dec_seq[((long)b * nT + (nT - 1)) * 1024 + h];
}

extern "C" void kernel_launch(void* const* d_in, const int* in_sizes, int n_in,
                              void* d_out, int out_size, void* d_ws, size_t ws_size,
                              hipStream_t stream) {
  const float* inputs  = (const float*)d_in[0];
  const float* outputs = (const float*)d_in[1];
  const float* eps     = (const float*)d_in[2];
  const float* enc_Wih = (const float*)d_in[3];
  const float* enc_Whh = (const float*)d_in[4];
  const float* enc_bih = (const float*)d_in[5];
  const float* enc_bhh = (const float*)d_in[6];
  const float* to_mu   = (const float*)d_in[7];
  const float* to_lsig = (const float*)d_in[8];
  const float* lsig_b  = (const float*)d_in[9];
  const float* W1 = (const float*)d_in[10];
  const float* b1 = (const float*)d_in[11];
  const float* W2 = (const float*)d_in[12];
  const float* b2 = (const float*)d_in[13];
  const float* W3 = (const float*)d_in[14];
  const float* b3 = (const float*)d_in[15];
  const float* gWih  = (const float*)d_in[16];
  const float* gWhh  = (const float*)d_in[17];
  const float* gbias = (const float*)d_in[18];

  char* ws = (char*)d_ws;
  size_t off = 0;
  auto alloc = [&](size_t bytes) { size_t o = off; off = (off + bytes + 255) & ~(size_t)255; return o; };
  size_t oWhhB  = alloc(64ull * SZ_WHH * 2);        // bf16 per-sample Whh
  size_t oRest  = alloc(64ull * REST_SZ * 4);       // fp32 psi remainder
  size_t oWtWhh = alloc(1024ull * 3072 * 4);
  size_t oWtWih = alloc(64ull * 3072 * 4);
  size_t ohA    = alloc(64ull * 1024 * 4);
  size_t ohB    = alloc(64ull * 1024 * 4);
  size_t oDec   = alloc(64ull * 64 * 1024 * 4);
  size_t oZ     = alloc(64 * nK * 4);
  size_t oA2    = alloc(64 * 30 * 4);
  (void)ws_size; (void)in_sizes; (void)n_in; (void)out_size;

  __hip_bfloat16* WhhB = (__hip_bfloat16*)(ws + oWhhB);
  float* Rest  = (float*)(ws + oRest);
  float* WtWhh = (float*)(ws + oWtWhh);
  float* WtWih = (float*)(ws + oWtWih);
  float* hA    = (float*)(ws + ohA);
  float* hB    = (float*)(ws + ohB);
  float* decS  = (float*)(ws + oDec);
  float* zlat  = (float*)(ws + oZ);
  float* a2    = (float*)(ws + oA2);

  float* out      = (float*)d_out;
  float* out_yh   = out;                        // 262144
  float* out_mu   = out + 262144;               // 448
  float* out_ls   = out + 262144 + 448;         // 448
  float* out_st   = out + 262144 + 896;         // 65536

  // 1) transpose encoder weights
  transpose_k<<<dim3(32, 96), dim3(32, 8), 0, stream>>>(enc_Whh, WtWhh, 3072, 1024);
  transpose_k<<<dim3(2, 96),  dim3(32, 8), 0, stream>>>(enc_Wih, WtWih, 3072, 64);

  // 2) encoder: h0 = 0, 64 steps
  hipMemsetAsync(hA, 0, 64ull * 1024 * 4, stream);
  for (int t = 0; t < nT; ++t) {
    const float* hin = (t & 1) ? hB : hA;
    float* hout      = (t & 1) ? hA : hB;
    enc_step_k<<<256, 256, 0, stream>>>(hin, hout, outputs, WtWhh, WtWih, enc_bih, enc_bhh, t);
  }
  // final h_enc is in hA (64 steps, even)

  // 3) latent
  latent_k<<<64, 64, 0, stream>>>(hA, to_mu, to_lsig, lsig_b, eps, out_mu, out_ls, zlat);

  // 4) hypernet small layers
  hyper_k<<<64, 256, 0, stream>>>(zlat, W1, b1, W2, b2, a2);

  // 5) psi materialization
  psi_k<<<(int)((N_PSI + 255) / 256), 256, 0, stream>>>(a2, W3, b3, WhhB, Rest);

  // 6) decoder: h0 = 0, 64 steps (reuse hA after latent consumed it)
  hipMemsetAsync(hA, 0, 64ull * 1024 * 4, stream);
  for (int t = 0; t < nT; ++t) {
    const float* hin = (t & 1) ? hB : hA;
    float* hout      = (t & 1) ? hA : hB;
    dec_step_k<<<256, 256, 0, stream>>>(hin, hout, inputs, gWih, gWhh, gbias, WhhB, Rest, decS, t);
  }

  // 7) readout + states
  readout_k<<<4096, 64, 0, stream>>>(decS, inputs, Rest, out_yh);
  copy_states_k<<<256, 256, 0, stream>>>(decS, out_st);
}

// Round 2
// 3872.636 us; speedup vs baseline: 2.8818x; 2.8818x over previous
//
#include <hip/hip_runtime.h>

// ---- problem constants ----
namespace {
constexpr int nT = 64;
constexpr int nK = 7;
constexpr long N_PSI = 1123776;
constexpr long SZ_WHH = 1048576;       // psi region 0: (1024,1024)
constexpr long REST_SZ = 75200;        // per-sample remaining psi elems
constexpr long R_BH = 0;               // (1024,)
constexpr long R_WIH = 1024;           // (8,1024)
constexpr long R_C = 9216;             // (1024,64)
constexpr long R_D = 74752;            // (8,56)
constexpr int NCH = 16;                // h-chunks per step kernel
constexpr int CHR = 64;                // rows per chunk (1024/16)
}

typedef __attribute__((ext_vector_type(4))) unsigned short us4;

__device__ __forceinline__ float b2f(unsigned short u) {
  return __uint_as_float(((unsigned int)u) << 16);
}
__device__ __forceinline__ unsigned short f2b(float f) {
  unsigned int u = __float_as_uint(f);
  return (unsigned short)((u + 0x7fffu + ((u >> 16) & 1u)) >> 16);
}

// ---------- one-time: transpose (rows,cols) fp32 -> bf16 out[c*rows + r] ----------
__global__ void transpose_bf16_k(const float* __restrict__ in, unsigned short* __restrict__ out,
                                 int rows, int cols) {
  __shared__ float tile[32][33];
  int x = blockIdx.x * 32 + threadIdx.x;
  int y = blockIdx.y * 32 + threadIdx.y;
  #pragma unroll
  for (int i = 0; i < 32; i += 8)
    if ((y + i) < rows && x < cols) tile[threadIdx.y + i][threadIdx.x] = in[(long)(y + i) * cols + x];
  __syncthreads();
  x = blockIdx.y * 32 + threadIdx.x;
  y = blockIdx.x * 32 + threadIdx.y;
  #pragma unroll
  for (int i = 0; i < 32; i += 8)
    if ((y + i) < cols && x < rows) out[(long)(y + i) * rows + x] = f2b(tile[threadIdx.x][threadIdx.y + i]);
}

__global__ void cvt_bf16_k(const float* __restrict__ in, unsigned short* __restrict__ out, long n) {
  long i = (long)blockIdx.x * 256 + threadIdx.x;
  if (i < n) out[i] = f2b(in[i]);
}

// ---------- bulk precompute: encoder gx (includes bih) ----------
__global__ __launch_bounds__(256) void enc_gx_k(const float* __restrict__ outputs,
                                                const unsigned short* __restrict__ WtWihB,
                                                const float* __restrict__ bih,
                                                unsigned short* __restrict__ gxE) {
  int g = blockIdx.x * 256 + threadIdx.x;       // 0..3071
  int b = blockIdx.y & 63, t = blockIdx.y >> 6;
  __shared__ float xs[64];
  if (threadIdx.x < 64) xs[threadIdx.x] = outputs[((long)b * nT + t) * 64 + threadIdx.x];
  __syncthreads();
  float acc = bih[g];
  #pragma unroll 8
  for (int i = 0; i < 64; ++i) acc += xs[i] * b2f(WtWihB[(long)i * 3072 + g]);
  gxE[((long)t * 64 + b) * 3072 + g] = f2b(acc);
}

// ---------- bulk precompute: decoder gx (includes gbias) ----------
__global__ __launch_bounds__(256) void dec_gx_k(const float* __restrict__ inputs,
                                                const float* __restrict__ gWih,
                                                const float* __restrict__ gbias,
                                                unsigned short* __restrict__ gxD) {
  int k = blockIdx.x * 256 + threadIdx.x;       // 0..2047
  int b = blockIdx.y & 63, t = blockIdx.y >> 6;
  __shared__ float xs[8];
  if (threadIdx.x < 8) xs[threadIdx.x] = inputs[((long)b * nT + t) * 8 + threadIdx.x];
  __syncthreads();
  float acc = gbias[k];
  #pragma unroll
  for (int i = 0; i < 8; ++i) acc += xs[i] * gWih[i * 2048 + k];
  gxD[((long)t * 64 + b) * 2048 + k] = f2b(acc);
}

// ---------- bulk precompute: x @ Wih_b per sample ----------
__global__ __launch_bounds__(256) void xW_k(const float* __restrict__ inputs,
                                            const float* __restrict__ Rest,
                                            unsigned short* __restrict__ xWb) {
  int k = blockIdx.x * 256 + threadIdx.x;       // 0..1023
  int b = blockIdx.y & 63, t = blockIdx.y >> 6;
  __shared__ float xs[8];
  if (threadIdx.x < 8) xs[threadIdx.x] = inputs[((long)b * nT + t) * 8 + threadIdx.x];
  __syncthreads();
  const float* RB = Rest + (long)b * REST_SZ + R_WIH;
  float acc = 0.f;
  #pragma unroll
  for (int i = 0; i < 8; ++i) acc += xs[i] * RB[(long)i * 1024 + k];
  xWb[((long)t * 64 + b) * 1024 + k] = f2b(acc);
}

// ---------- encoder step: partial (h-chunked, 2 samples/thread) ----------
__global__ __launch_bounds__(256) void enc_partial_k(
    const float* __restrict__ h_in, const unsigned short* __restrict__ W,   // [1024][3072] bf16
    float* __restrict__ pR, float* __restrict__ pZ, float* __restrict__ pN) {
  int c = blockIdx.x, sp = blockIdx.y;
  int b0 = sp * 2, b1 = b0 + 1;
  int e0 = threadIdx.x * 4;
  __shared__ float h0s[CHR], h1s[CHR];
  if (threadIdx.x < CHR) h0s[threadIdx.x] = h_in[b0 * 1024 + c * CHR + threadIdx.x];
  else if (threadIdx.x < 2 * CHR) h1s[threadIdx.x - CHR] = h_in[b1 * 1024 + c * CHR + (threadIdx.x - CHR)];
  __syncthreads();
  float ar0[4] = {}, az0[4] = {}, an0[4] = {}, ar1[4] = {}, az1[4] = {}, an1[4] = {};
  const unsigned short* Wb = W + (long)(c * CHR) * 3072 + e0;
  #pragma unroll 4
  for (int j = 0; j < CHR; ++j) {
    us4 wr = *(const us4*)(Wb + (long)j * 3072);
    us4 wz = *(const us4*)(Wb + (long)j * 3072 + 1024);
    us4 wn = *(const us4*)(Wb + (long)j * 3072 + 2048);
    float hv0 = h0s[j], hv1 = h1s[j];
    #pragma unroll
    for (int q = 0; q < 4; ++q) {
      float fr = b2f(wr[q]), fz = b2f(wz[q]), fn = b2f(wn[q]);
      ar0[q] += hv0 * fr; az0[q] += hv0 * fz; an0[q] += hv0 * fn;
      ar1[q] += hv1 * fr; az1[q] += hv1 * fz; an1[q] += hv1 * fn;
    }
  }
  long i0 = ((long)c * 64 + b0) * 1024 + e0;
  long i1 = i0 + 1024;
  *(float4*)(pR + i0) = make_float4(ar0[0], ar0[1], ar0[2], ar0[3]);
  *(float4*)(pZ + i0) = make_float4(az0[0], az0[1], az0[2], az0[3]);
  *(float4*)(pN + i0) = make_float4(an0[0], an0[1], an0[2], an0[3]);
  *(float4*)(pR + i1) = make_float4(ar1[0], ar1[1], ar1[2], ar1[3]);
  *(float4*)(pZ + i1) = make_float4(az1[0], az1[1], az1[2], az1[3]);
  *(float4*)(pN + i1) = make_float4(an1[0], an1[1], an1[2], an1[3]);
}

// ---------- encoder step: reduce + gates ----------
__global__ __launch_bounds__(256) void enc_reduce_k(
    const float* __restrict__ h_in, float* __restrict__ h_out,
    const float* __restrict__ pR, const float* __restrict__ pZ, const float* __restrict__ pN,
    const unsigned short* __restrict__ gxE, const float* __restrict__ bhh, int t) {
  int b = blockIdx.x >> 2;
  int e = (blockIdx.x & 3) * 256 + threadIdx.x;
  float sr = 0.f, sz = 0.f, sn = 0.f;
  #pragma unroll
  for (int c = 0; c < NCH; ++c) {
    long base = ((long)c * 64 + b) * 1024 + e;
    sr += pR[base]; sz += pZ[base]; sn += pN[base];
  }
  long gb = ((long)t * 64 + b) * 3072;
  float xr = b2f(gxE[gb + e]), xz = b2f(gxE[gb + 1024 + e]), xn = b2f(gxE[gb + 2048 + e]);
  float hr = sr + bhh[e], hz = sz + bhh[1024 + e], hn = sn + bhh[2048 + e];
  float r = 1.f / (1.f + __expf(-(xr + hr)));
  float z = 1.f / (1.f + __expf(-(xz + hz)));
  float n = tanhf(xn + r * hn);
  h_out[b * 1024 + e] = (1.f - z) * n + z * h_in[b * 1024 + e];
}

// ---------- latent ----------
__global__ void latent_k(const float* __restrict__ h_enc,
                         const float* __restrict__ to_mu, const float* __restrict__ to_lsig,
                         const float* __restrict__ lsig_bias, const float* __restrict__ eps,
                         float* __restrict__ out_mu, float* __restrict__ out_lsig,
                         float* __restrict__ zlat) {
  int b = blockIdx.x;
  __shared__ float hs[1024];
  for (int i = threadIdx.x; i < 1024; i += blockDim.x) hs[i] = h_enc[b * 1024 + i];
  __syncthreads();
  int k = threadIdx.x;
  if (k < nK) {
    float am = 0.f, as = 0.f;
    for (int h = 0; h < 1024; ++h) { float hv = hs[h]; am += hv * to_mu[h * nK + k]; as += hv * to_lsig[h * nK + k]; }
    float ls = as + lsig_bias[k];
    out_mu[b * nK + k] = am;
    out_lsig[b * nK + k] = ls;
    zlat[b * nK + k] = am + eps[b * nK + k] * __expf(ls);
  }
}

// ---------- hypernet layers 1-2 ----------
__global__ __launch_bounds__(256) void hyper_k(const float* __restrict__ zlat,
                                               const float* __restrict__ W1, const float* __restrict__ b1,
                                               const float* __restrict__ W2, const float* __restrict__ b2,
                                               float* __restrict__ a2out) {
  int b = blockIdx.x;
  __shared__ float a1[1024];
  __shared__ float zv[nK];
  if (threadIdx.x < nK) zv[threadIdx.x] = zlat[b * nK + threadIdx.x];
  __syncthreads();
  for (int j = threadIdx.x; j < 1024; j += 256) {
    float acc = b1[j];
    #pragma unroll
    for (int i = 0; i < nK; ++i) acc += zv[i] * W1[i * 1024 + j];
    a1[j] = tanhf(acc);
  }
  __syncthreads();
  int l = threadIdx.x >> 3;
  int s = threadIdx.x & 7;
  if (l < 30) {
    float acc = 0.f;
    for (int j = s; j < 1024; j += 8) acc += a1[j] * W2[j * 30 + l];
    acc += __shfl_xor(acc, 4);
    acc += __shfl_xor(acc, 2);
    acc += __shfl_xor(acc, 1);
    if (s == 0) a2out[b * 30 + l] = acc + b2[l];
  }
}

// ---------- psi materialization ----------
__global__ __launch_bounds__(256) void psi_k(const float* __restrict__ a2,
                                             const float* __restrict__ W3, const float* __restrict__ b3,
                                             unsigned short* __restrict__ WhhB, float* __restrict__ Rest) {
  __shared__ float sa[64 * 30];
  for (int i = threadIdx.x; i < 64 * 30; i += 256) sa[i] = a2[i];
  long n = (long)blockIdx.x * 256 + threadIdx.x;
  __syncthreads();
  if (n >= N_PSI) return;
  float w[30];
  #pragma unroll
  for (int l = 0; l < 30; ++l) w[l] = W3[(long)l * N_PSI + n];
  float bb = b3[n];
  bool isWhh = (n < SZ_WHH);
  for (int b = 0; b < 64; ++b) {
    float acc = bb;
    const float* ab = &sa[b * 30];
    #pragma unroll
    for (int l = 0; l < 30; ++l) acc += ab[l] * w[l];
    if (isWhh) WhhB[(long)b * SZ_WHH + n] = f2b(acc);
    else       Rest[(long)b * REST_SZ + (n - SZ_WHH)] = acc;
  }
}

// ---------- decoder step: partial (h-chunked, 2 samples/thread) ----------
__global__ __launch_bounds__(256) void dec_partial_k(
    const float* __restrict__ h_in,
    const unsigned short* __restrict__ WhhB,   // [B][1024][1024] bf16
    const unsigned short* __restrict__ gWhhB,  // [1024][2048] bf16
    float* __restrict__ pZ, float* __restrict__ pR, float* __restrict__ pW) {
  int c = blockIdx.x, sp = blockIdx.y;
  int b0 = sp * 2, b1 = b0 + 1;
  int k0 = threadIdx.x * 4;
  __shared__ float h0s[CHR], h1s[CHR];
  if (threadIdx.x < CHR) h0s[threadIdx.x] = h_in[b0 * 1024 + c * CHR + threadIdx.x];
  else if (threadIdx.x < 2 * CHR) h1s[threadIdx.x - CHR] = h_in[b1 * 1024 + c * CHR + (threadIdx.x - CHR)];
  __syncthreads();
  float az0[4] = {}, ar0[4] = {}, aw0[4] = {}, az1[4] = {}, ar1[4] = {}, aw1[4] = {};
  const unsigned short* G = gWhhB + (long)(c * CHR) * 2048 + k0;
  const unsigned short* W0 = WhhB + (long)b0 * SZ_WHH + (long)(c * CHR) * 1024 + k0;
  const unsigned short* W1p = WhhB + (long)b1 * SZ_WHH + (long)(c * CHR) * 1024 + k0;
  #pragma unroll 4
  for (int j = 0; j < CHR; ++j) {
    us4 wz = *(const us4*)(G + (long)j * 2048);
    us4 wr = *(const us4*)(G + (long)j * 2048 + 1024);
    us4 w0 = *(const us4*)(W0 + (long)j * 1024);
    us4 w1 = *(const us4*)(W1p + (long)j * 1024);
    float hv0 = h0s[j], hv1 = h1s[j];
    #pragma unroll
    for (int q = 0; q < 4; ++q) {
      float fz = b2f(wz[q]), fr = b2f(wr[q]), f0 = b2f(w0[q]), f1 = b2f(w1[q]);
      az0[q] += hv0 * fz; ar0[q] += hv0 * fr; aw0[q] += hv0 * f0;
      az1[q] += hv1 * fz; ar1[q] += hv1 * fr; aw1[q] += hv1 * f1;
    }
  }
  long i0 = ((long)c * 64 + b0) * 1024 + k0;
  long i1 = i0 + 1024;
  *(float4*)(pZ + i0) = make_float4(az0[0], az0[1], az0[2], az0[3]);
  *(float4*)(pR + i0) = make_float4(ar0[0], ar0[1], ar0[2], ar0[3]);
  *(float4*)(pW + i0) = make_float4(aw0[0], aw0[1], aw0[2], aw0[3]);
  *(float4*)(pZ + i1) = make_float4(az1[0], az1[1], az1[2], az1[3]);
  *(float4*)(pR + i1) = make_float4(ar1[0], ar1[1], ar1[2], ar1[3]);
  *(float4*)(pW + i1) = make_float4(aw1[0], aw1[1], aw1[2], aw1[3]);
}

// ---------- decoder step: reduce + gates + h update ----------
__global__ __launch_bounds__(256) void dec_reduce_k(
    const float* __restrict__ h_in, float* __restrict__ h_out,
    const float* __restrict__ pZ, const float* __restrict__ pR, const float* __restrict__ pW,
    const unsigned short* __restrict__ gxD, const unsigned short* __restrict__ xWb,
    const float* __restrict__ Rest, float* __restrict__ dec_seq, int t) {
  int b = blockIdx.x >> 2;
  int k = (blockIdx.x & 3) * 256 + threadIdx.x;
  float sz = 0.f, sr = 0.f, sw = 0.f;
  #pragma unroll
  for (int c = 0; c < NCH; ++c) {
    long base = ((long)c * 64 + b) * 1024 + k;
    sz += pZ[base]; sr += pR[base]; sw += pW[base];
  }
  long gb = ((long)t * 64 + b) * 2048;
  float gz = b2f(gxD[gb + k]), gr = b2f(gxD[gb + 1024 + k]);
  float z = 1.f / (1.f + __expf(-(gz + sz)));
  float r = 1.f / (1.f + __expf(-(gr + sr)));
  float hW = sw + Rest[(long)b * REST_SZ + R_BH + k];
  float xw = b2f(xWb[((long)t * 64 + b) * 1024 + k]);
  float eta = tanhf(xw + r * tanhf(hW));
  float h = h_in[b * 1024 + k];
  float hn = z * h + (1.f - z) * eta;
  h_out[b * 1024 + k] = hn;
  dec_seq[((long)b * nT + t) * 1024 + k] = hn;
}

// ---------- readout ----------
__global__ __launch_bounds__(256) void readout_k(
    const float* __restrict__ dec_seq, const float* __restrict__ inputs,
    const float* __restrict__ Rest, float* __restrict__ yhats) {
  int bt = blockIdx.x; int b = bt >> 6;
  __shared__ float ss[1024];
  __shared__ float part[4][64];
  for (int i = threadIdx.x; i < 1024; i += 256) ss[i] = dec_seq[(long)bt * 1024 + i];
  __syncthreads();
  int w = threadIdx.x >> 6, m = threadIdx.x & 63;
  const float* C = Rest + (long)b * REST_SZ + R_C;
  float acc = 0.f;
  #pragma unroll 4
  for (int h = w * 256; h < w * 256 + 256; ++h) acc += ss[h] * C[(long)h * 64 + m];
  part[w][m] = acc;
  __syncthreads();
  if (threadIdx.x < 64) {
    float a = part[0][m] + part[1][m] + part[2][m] + part[3][m];
    if (m < 8) {
      a += inputs[(long)bt * 8 + m];
    } else {
      const float* D = Rest + (long)b * REST_SZ + R_D;
      #pragma unroll
      for (int i = 0; i < 8; ++i) a += inputs[(long)bt * 8 + i] * D[i * 56 + (m - 8)];
    }
    yhats[(long)bt * 64 + m] = a;
  }
}

__global__ void copy_states_k(const float* __restrict__ dec_seq, float* __restrict__ states) {
  int i = blockIdx.x * 256 + threadIdx.x;
  int b = i >> 10, h = i & 1023;
  states[i] = dec_seq[((long)b * nT + (nT - 1)) * 1024 + h];
}

extern "C" void kernel_launch(void* const* d_in, const int* in_sizes, int n_in,
                              void* d_out, int out_size, void* d_ws, size_t ws_size,
                              hipStream_t stream) {
  const float* inputs  = (const float*)d_in[0];
  const float* outputs = (const float*)d_in[1];
  const float* eps     = (const float*)d_in[2];
  const float* enc_Wih = (const float*)d_in[3];
  const float* enc_Whh = (const float*)d_in[4];
  const float* enc_bih = (const float*)d_in[5];
  const float* enc_bhh = (const float*)d_in[6];
  const float* to_mu   = (const float*)d_in[7];
  const float* to_lsig = (const float*)d_in[8];
  const float* lsig_b  = (const float*)d_in[9];
  const float* W1 = (const float*)d_in[10];
  const float* b1 = (const float*)d_in[11];
  const float* W2 = (const float*)d_in[12];
  const float* b2 = (const float*)d_in[13];
  const float* W3 = (const float*)d_in[14];
  const float* b3 = (const float*)d_in[15];
  const float* gWih  = (const float*)d_in[16];
  const float* gWhh  = (const float*)d_in[17];
  const float* gbias = (const float*)d_in[18];

  char* ws = (char*)d_ws;
  size_t off = 0;
  auto alloc = [&](size_t bytes) { size_t o = off; off = (off + bytes + 255) & ~(size_t)255; return o; };
  size_t oWhhB   = alloc(64ull * SZ_WHH * 2);        // bf16 per-sample Whh
  size_t oRest   = alloc(64ull * REST_SZ * 4);       // fp32 psi remainder
  size_t ogWhhB  = alloc(1024ull * 2048 * 2);        // bf16 gru_Whh
  size_t oWtWhhB = alloc(1024ull * 3072 * 2);        // bf16 enc_Whh^T
  size_t oWtWihB = alloc(64ull * 3072 * 2);          // bf16 enc_Wih^T
  size_t ogxE    = alloc(64ull * 64 * 3072 * 2);     // bf16 encoder gx (incl bih)
  size_t ogxD    = alloc(64ull * 64 * 2048 * 2);     // bf16 decoder gx (incl gbias)
  size_t oxWb    = alloc(64ull * 64 * 1024 * 2);     // bf16 x@Wih_b
  size_t opA     = alloc((size_t)NCH * 64 * 1024 * 4);
  size_t opB     = alloc((size_t)NCH * 64 * 1024 * 4);
  size_t opC     = alloc((size_t)NCH * 64 * 1024 * 4);
  size_t ohA     = alloc(64ull * 1024 * 4);
  size_t ohB     = alloc(64ull * 1024 * 4);
  size_t oDec    = alloc(64ull * 64 * 1024 * 4);
  size_t oZ      = alloc(64 * nK * 4);
  size_t oA2     = alloc(64 * 30 * 4);
  (void)ws_size; (void)in_sizes; (void)n_in; (void)out_size;

  unsigned short* WhhB   = (unsigned short*)(ws + oWhhB);
  float*          Rest   = (float*)(ws + oRest);
  unsigned short* gWhhB  = (unsigned short*)(ws + ogWhhB);
  unsigned short* WtWhhB = (unsigned short*)(ws + oWtWhhB);
  unsigned short* WtWihB = (unsigned short*)(ws + oWtWihB);
  unsigned short* gxE    = (unsigned short*)(ws + ogxE);
  unsigned short* gxD    = (unsigned short*)(ws + ogxD);
  unsigned short* xWb    = (unsigned short*)(ws + oxWb);
  float* pA   = (float*)(ws + opA);
  float* pB   = (float*)(ws + opB);
  float* pC   = (float*)(ws + opC);
  float* hA   = (float*)(ws + ohA);
  float* hB   = (float*)(ws + ohB);
  float* decS = (float*)(ws + oDec);
  float* zlat = (float*)(ws + oZ);
  float* a2   = (float*)(ws + oA2);

  float* out    = (float*)d_out;
  float* out_yh = out;                 // 262144
  float* out_mu = out + 262144;        // 448
  float* out_ls = out + 262144 + 448;  // 448
  float* out_st = out + 262144 + 896;  // 65536

  // 1) weight preprocessing (bf16)
  transpose_bf16_k<<<dim3(32, 96), dim3(32, 8), 0, stream>>>(enc_Whh, WtWhhB, 3072, 1024);
  transpose_bf16_k<<<dim3(2, 96),  dim3(32, 8), 0, stream>>>(enc_Wih, WtWihB, 3072, 64);
  cvt_bf16_k<<<(int)((1024ull * 2048 + 255) / 256), 256, 0, stream>>>(gWhh, gWhhB, 1024 * 2048);

  // 2) bulk encoder gx
  enc_gx_k<<<dim3(12, 4096), 256, 0, stream>>>(outputs, WtWihB, enc_bih, gxE);

  // 3) encoder recurrence
  hipMemsetAsync(hA, 0, 64ull * 1024 * 4, stream);
  for (int t = 0; t < nT; ++t) {
    const float* hin = (t & 1) ? hB : hA;
    float* hout      = (t & 1) ? hA : hB;
    enc_partial_k<<<dim3(NCH, 32), 256, 0, stream>>>(hin, WtWhhB, pA, pB, pC);
    enc_reduce_k<<<256, 256, 0, stream>>>(hin, hout, pA, pB, pC, gxE, enc_bhh, t);
  }

  // 4) latent + hypernet + psi
  latent_k<<<64, 64, 0, stream>>>(hA, to_mu, to_lsig, lsig_b, eps, out_mu, out_ls, zlat);
  hyper_k<<<64, 256, 0, stream>>>(zlat, W1, b1, W2, b2, a2);
  psi_k<<<(int)((N_PSI + 255) / 256), 256, 0, stream>>>(a2, W3, b3, WhhB, Rest);

  // 5) bulk decoder gx and x@Wih_b
  dec_gx_k<<<dim3(8, 4096), 256, 0, stream>>>(inputs, gWih, gbias, gxD);
  xW_k<<<dim3(4, 4096), 256, 0, stream>>>(inputs, Rest, xWb);

  // 6) decoder recurrence
  hipMemsetAsync(hA, 0, 64ull * 1024 * 4, stream);
  for (int t = 0; t < nT; ++t) {
    const float* hin = (t & 1) ? hB : hA;
    float* hout      = (t & 1) ? hA : hB;
    dec_partial_k<<<dim3(NCH, 32), 256, 0, stream>>>(hin, WhhB, gWhhB, pA, pB, pC);
    dec_reduce_k<<<256, 256, 0, stream>>>(hin, hout, pA, pB, pC, gxD, xWb, Rest, decS, t);
  }

  // 7) readout + states
  readout_k<<<4096, 256, 0, stream>>>(decS, inputs, Rest, out_yh);
  copy_states_k<<<256, 256, 0, stream>>>(decS, out_st);
}